// Round 4
// baseline (115.033 us; speedup 1.0000x reference)
//
#include <hip/hip_runtime.h>
#include <math.h>

#define NB 64
#define NO 32
#define NP 5456
#define NC 80
#define NSLOT 45
#define EPSF 1e-7f

// ---------- focal pieces ----------
// negative term: 0.75 * sigmoid(x)^2 * softplus(x)
__device__ __forceinline__ float focal_neg(float x) {
    float ax  = fabsf(x);
    float eax = __expf(-ax);
    float l1  = __logf(1.f + eax);
    float sp  = fmaxf(x, 0.f) + l1;          // softplus(x)
    float q   = __builtin_amdgcn_rcpf(1.f + eax);
    float p   = (x >= 0.f) ? q : eax * q;    // sigmoid(x)
    return 0.75f * p * p * sp;
}
// positive term: 0.25 * (1-p)^2 * softplus(-x)
__device__ __forceinline__ float focal_pos(float x) {
    float ax  = fabsf(x);
    float eax = __expf(-ax);
    float l1  = __logf(1.f + eax);
    float spn = fmaxf(-x, 0.f) + l1;         // softplus(-x)
    float q   = __builtin_amdgcn_rcpf(1.f + eax);
    float p   = (x >= 0.f) ? q : eax * q;
    float om  = 1.f - p;
    return 0.25f * om * om * spn;
}

// pack (distance, idx) into one monotonic u64 key: d >= 0 so IEEE bits are
// order-preserving; low 32 bits = idx -> exact lex (d, idx) tie semantics.
__device__ __forceinline__ unsigned long long pkkey(float d, int j) {
    return ((unsigned long long)__float_as_uint(d) << 32) | (unsigned)j;
}

// ---------- 1) fat kernel: focal streaming (HBM-bound) || topk (VALU-bound) ----
// grid = 4608 = 512 groups x 9 blocks; r<4 -> focal block (2048), else topk (2560).
__global__ __launch_bounds__(256) void fused_main(
    const float4* __restrict__ sc4,      // [NB*NP*NC/4]
    const float4* __restrict__ boxes,    // [NB*NO]
    const float*  __restrict__ priors,   // [NP*4]
    int*   __restrict__ ci,              // [NB*NO*NSLOT]
    float* __restrict__ cp,              // [NB*NO*NSLOT]
    float* __restrict__ partial,         // [2048]
    int total4)
{
    const unsigned bid = blockIdx.x;
    const unsigned grp = bid / 9u, r = bid - grp * 9u;

    if (r < 4u) {
        // ---------------- focal ----------------
        const int fb = (int)(grp * 4u + r);
        const int half4 = total4 >> 1;
        float lsum = 0.f;
        for (int e4 = fb * 256 + threadIdx.x; e4 < half4; e4 += 2048 * 256) {
            float4 v1 = sc4[e4];
            float4 v2 = sc4[e4 + half4];           // second independent stream
            lsum += focal_neg(v1.x) + focal_neg(v1.y) + focal_neg(v1.z) + focal_neg(v1.w);
            lsum += focal_neg(v2.x) + focal_neg(v2.y) + focal_neg(v2.z) + focal_neg(v2.w);
        }
        #pragma unroll
        for (int off = 32; off > 0; off >>= 1) lsum += __shfl_down(lsum, off);
        __shared__ float wsum[4];
        const int lane = threadIdx.x & 63, wid = threadIdx.x >> 6;
        if (lane == 0) wsum[wid] = lsum;
        __syncthreads();
        if (threadIdx.x == 0) partial[fb] = wsum[0] + wsum[1] + wsum[2] + wsum[3];
    } else {
        // ---------------- topk: one wave per (b, o, level) ----------------
        const int tk   = (int)(grp * 5u + (r - 4u));
        const int lane = threadIdx.x & 63;
        const int task = tk * 4 + (threadIdx.x >> 6);
        const int l    = task >> 11;               // 0..4 (uniform per wave)
        const int bo   = task & 2047;              // b*NO + o

        const int S    = (l==0)?4096:(l==1)?1024:(l==2)?256:(l==3)?64:16;
        const int base = (l==0)?0:(l==1)?4096:(l==2)?5120:(l==3)?5376:5440;

        const float4 a = ((const float4*)priors, boxes)[bo];
        const float gx = (a.x + a.z) * 0.5f, gy = (a.y + a.w) * 0.5f;

        // per-lane sorted top-9 keys (ascending); statically indexed only
        unsigned long long bk[9];
        #pragma unroll
        for (int k = 0; k < 9; ++k) bk[k] = ~0ull;

        const float2* pr2 = (const float2*)priors; // priors[i].xy = pr2[2i]
        for (int j = lane; j < S; j += 64) {
            float2 c = pr2[(base + j) * 2];
            float dx = gx - c.x, dy = gy - c.y;
            float d = sqrtf(dx * dx + dy * dy);
            unsigned long long key = pkkey(d, j);
            if (key < bk[8]) {
                bk[8] = key;
                #pragma unroll
                for (int k = 8; k > 0; --k)
                    if (bk[k] < bk[k-1]) {
                        unsigned long long t = bk[k]; bk[k] = bk[k-1]; bk[k-1] = t;
                    }
            }
        }

        // 6-stage xor merge: each stage pulls partner's sorted 9 (independent
        // shfls) and insertion-merges (keys unique across lanes -> no dup risk).
        #pragma unroll
        for (int st = 0; st < 6; ++st) {
            const int off = 1 << st;
            unsigned long long pk[9];
            #pragma unroll
            for (int q = 0; q < 9; ++q) pk[q] = __shfl_xor(bk[q], off);
            #pragma unroll
            for (int q = 0; q < 9; ++q) {
                unsigned long long e = pk[q];
                if (e < bk[8]) {
                    bk[8] = e;
                    #pragma unroll
                    for (int k = 8; k > 0; --k)
                        if (bk[k] < bk[k-1]) {
                            unsigned long long t = bk[k]; bk[k] = bk[k-1]; bk[k-1] = t;
                        }
                }
            }
        }

        // all lanes now hold identical sorted top-9; lane k takes bk[k]
        unsigned long long mykey = bk[0];
        #pragma unroll
        for (int k = 1; k < 9; ++k) if (lane == k) mykey = bk[k];

        if (lane < 9) {
            int win = (int)(unsigned)(mykey & 0xffffffffull);
            const float4* pr4 = (const float4*)priors;
            float4 pv = pr4[base + win];
            float bx0 = pv.x - pv.z * 0.5f, by0 = pv.y - pv.w * 0.5f;
            float bx1 = pv.x + pv.z * 0.5f, by1 = pv.y + pv.w * 0.5f;
            float w = fmaxf(fminf(a.z, bx1) - fmaxf(a.x, bx0), 0.f);
            float h = fmaxf(fminf(a.w, by1) - fmaxf(a.y, by0), 0.f);
            float inter  = w * h;
            float area_a = (a.z - a.x) * (a.w - a.y);
            float area_b = (bx1 - bx0) * (by1 - by0);
            float iou = inter / (area_a + area_b - inter + EPSF);
            int idx = bo * NSLOT + l * 9 + lane;
            ci[idx] = base + win;
            cp[idx] = iou;
        }
    }
}

// ---------- 2) threshold + argmax + decode + ciou + label corr (1 wave/image) ----
__global__ __launch_bounds__(64) void finish_kernel(
    const float4* __restrict__ locs,     // [NB*NP]
    const float4* __restrict__ boxes,    // [NB*NO]
    const int*    __restrict__ labels,   // [NB*NO]
    const float4* __restrict__ priors,   // [NP]
    const float*  __restrict__ scores,   // [NB*NP*NC]
    const int*    __restrict__ ci,
    const float*  __restrict__ cp,
    float* __restrict__ corr,            // [NB] focal pos-correction sum
    int*   __restrict__ npb,             // [NB] distinct positive priors
    float* __restrict__ ciouS,           // [NB] ciou loss sum
    int*   __restrict__ ciouC)           // [NB] matched slot count
{
    const int b = blockIdx.x;
    const int t = threadIdx.x;           // 64 threads = 1 wave

    __shared__ int    s_ci[NO * NSLOT];
    __shared__ float  s_io[NO * NSLOT];
    __shared__ int    s_pidx[NSLOT], s_ob[NSLOT], s_match[NSLOT];
    __shared__ float4 s_dec[NSLOT];

    const int4*   gci = (const int4*)(ci + b * NO * NSLOT);
    const float4* gcp = (const float4*)(cp + b * NO * NSLOT);
    int4*   sci4 = (int4*)s_ci;
    float4* sio4 = (float4*)s_io;
    for (int k = t; k < NO * NSLOT / 4; k += 64) { sci4[k] = gci[k]; sio4[k] = gcp[k]; }
    __syncthreads();

    // per-GT threshold (mean + std ddof=1 over 45) and masked iou (in place)
    if (t < NO) {
        float sum = 0.f;
        #pragma unroll
        for (int k = 0; k < NSLOT; ++k) sum += s_io[t * NSLOT + k];
        float mean = sum / 45.f;
        float var = 0.f;
        #pragma unroll
        for (int k = 0; k < NSLOT; ++k) { float d = s_io[t * NSLOT + k] - mean; var += d * d; }
        float thr = mean + sqrtf(var / 44.f);
        float4 a = boxes[b * NO + t];
        for (int k = 0; k < NSLOT; ++k) {
            float4 pv = priors[s_ci[t * NSLOT + k]];
            bool inside = (a.x < pv.x) && (pv.x < a.z) && (a.y < pv.y) && (pv.y < a.w);
            float pov = s_io[t * NSLOT + k];
            s_io[t * NSLOT + k] = (pov > thr && inside) ? pov : 0.f;
        }
    }
    __syncthreads();

    // per-slot argmax over GTs (first max), decode
    if (t < NSLOT) {
        float bv = s_io[t]; int ob = 0;
        for (int oo = 1; oo < NO; ++oo) {
            float v = s_io[oo * NSLOT + t];
            if (v > bv) { bv = v; ob = oo; }
        }
        int match = bv > 0.f;
        int pidx = s_ci[ob * NSLOT + t];
        s_pidx[t] = pidx; s_ob[t] = ob; s_match[t] = match;
        float4 lc = locs[b * NP + pidx];
        float4 pv = priors[pidx];
        float cx = lc.x * pv.z / 10.f + pv.x;
        float cy = lc.y * pv.w / 10.f + pv.y;
        float wd = expf(lc.z / 5.f) * pv.z;
        float hd = expf(lc.w / 5.f) * pv.w;
        s_dec[t] = make_float4(cx - wd * 0.5f, cy - hd * 0.5f,
                               cx + wd * 0.5f, cy + hd * 0.5f);
    }
    __syncthreads();

    const int matched = (t < NSLOT) ? s_match[t] : 0;

    // ciou for matched slots (all in registers/LDS — never hits global)
    float cl = 0.f;
    if (matched) {
        float4 p = s_dec[t], t4 = boxes[b * NO + s_ob[t]];
        float pw = p.z - p.x, ph = p.w - p.y;
        float tw = t4.z - t4.x, th = t4.w - t4.y;
        float iw = fmaxf(fminf(p.z, t4.z) - fmaxf(p.x, t4.x), 0.f);
        float ih = fmaxf(fminf(p.w, t4.w) - fmaxf(p.y, t4.y), 0.f);
        float inter = iw * ih;
        float uni = pw * ph + tw * th - inter;
        float iou = inter / (uni + EPSF);
        float cw = fmaxf(p.z, t4.z) - fminf(p.x, t4.x);
        float ch = fmaxf(p.w, t4.w) - fminf(p.y, t4.y);
        float c2 = cw * cw + ch * ch + EPSF;
        float ddx = p.x + p.z - t4.x - t4.z, ddy = p.y + p.w - t4.y - t4.w;
        float rho2 = (ddx * ddx + ddy * ddy) * 0.25f;
        float dv = atanf(tw / (th + EPSF)) - atanf(pw / (ph + EPSF));
        float v = (float)(4.0 / (M_PI * M_PI)) * dv * dv;
        float al = v / (1.f - iou + v + EPSF);
        cl = 1.f - iou + rho2 / c2 + al * v;
    }

    // last-writer-wins label resolution -> focal pos-correction; first-occ count
    float mycorr = 0.f; int firstocc = 0;
    if (matched) {
        bool last = true, first = true;
        for (int s2 = t + 1; s2 < NSLOT; ++s2)
            if (s_match[s2] && s_pidx[s2] == s_pidx[t]) last = false;
        for (int s2 = 0; s2 < t; ++s2)
            if (s_match[s2] && s_pidx[s2] == s_pidx[t]) first = false;
        if (last) {
            int lab = labels[b * NO + s_ob[t]];
            float x = scores[((size_t)b * NP + s_pidx[t]) * NC + (lab - 1)];
            mycorr = focal_pos(x) - focal_neg(x);
        }
        firstocc = first;
    }

    unsigned long long ballm = __ballot(matched);
    unsigned long long ballf = __ballot(firstocc);
    #pragma unroll
    for (int off = 32; off > 0; off >>= 1) {
        cl     += __shfl_down(cl, off);
        mycorr += __shfl_down(mycorr, off);
    }
    if (t == 0) {
        corr[b]  = mycorr;
        npb[b]   = (int)__popcll(ballf);
        ciouS[b] = cl;
        ciouC[b] = (int)__popcll(ballm);
    }
}

// ---------- 3) final combine (single block) ----------
__global__ __launch_bounds__(256) void combine_kernel(
    const float* __restrict__ partial,   // [2048]
    const float* __restrict__ corr,      // [NB]
    const int*   __restrict__ npb,       // [NB]
    const float* __restrict__ ciouS,     // [NB]
    const int*   __restrict__ ciouC,     // [NB]
    float* __restrict__ out)
{
    const int t = threadIdx.x;
    double fsum = 0.0;
    for (int i = t; i < 2048; i += 256) fsum += (double)partial[i];

    float crs = 0.f, cs = 0.f; int np = 0, cc = 0;
    if (t < NB) { crs = corr[t]; np = npb[t]; cs = ciouS[t]; cc = ciouC[t]; }

    #pragma unroll
    for (int off = 32; off > 0; off >>= 1) {
        fsum += __shfl_down(fsum, off);
        crs  += __shfl_down(crs, off);
        cs   += __shfl_down(cs, off);
        np   += __shfl_down(np, off);
        cc   += __shfl_down(cc, off);
    }
    __shared__ double sd[4];
    const int lane = t & 63, wid = t >> 6;
    if (lane == 0) sd[wid] = fsum;
    __syncthreads();
    if (t == 0) {
        double ftot = sd[0] + sd[1] + sd[2] + sd[3] + (double)crs;
        int npv = np < 1 ? 1 : np;
        int ccv = cc < 1 ? 1 : cc;
        out[0] = (float)(ftot / (double)npv + (double)cs / (double)ccv);
    }
}

extern "C" void kernel_launch(void* const* d_in, const int* in_sizes, int n_in,
                              void* d_out, int out_size, void* d_ws, size_t ws_size,
                              hipStream_t stream)
{
    const float* locs   = (const float*)d_in[0];
    const float* scores = (const float*)d_in[1];
    const float* boxes  = (const float*)d_in[2];
    const int*   labels = (const int*)d_in[3];
    const float* priors = (const float*)d_in[4];

    char* ws = (char*)d_ws;
    int*   ci      = (int*)(ws + 0);                      // 92160 ints = 368640 B
    float* cp      = (float*)(ws + 368640);               // 368640 B
    float* partial = (float*)(ws + 737280);               // 8192 B
    float* corr    = (float*)(ws + 745472);
    int*   npb     = (int*)(ws + 745728);
    float* ciouS   = (float*)(ws + 745984);
    int*   ciouC   = (int*)(ws + 746240);

    // no memsets: partial/corr/npb/ciouS/ciouC are written unconditionally
    // by every owning block each call; ci/cp fully rewritten. Deterministic.

    const int total4 = NB * NP * NC / 4;
    fused_main<<<4608, 256, 0, stream>>>(
        (const float4*)scores, (const float4*)boxes, priors,
        ci, cp, partial, total4);

    finish_kernel<<<NB, 64, 0, stream>>>(
        (const float4*)locs, (const float4*)boxes, labels,
        (const float4*)priors, scores, ci, cp, corr, npb, ciouS, ciouC);

    combine_kernel<<<1, 256, 0, stream>>>(partial, corr, npb, ciouS, ciouC, (float*)d_out);
}

// Round 5
// 54.418 us; speedup vs baseline: 2.1139x; 2.1139x over previous
//
#include <hip/hip_runtime.h>
#include <math.h>

#define NB 64
#define NO 32
#define NP 5456
#define NC 80
#define NSLOT 45
#define EPSF 1e-7f
#define INF __builtin_inff()

// ---------- focal pieces ----------
// negative term: 0.75 * sigmoid(x)^2 * softplus(x)
__device__ __forceinline__ float focal_neg(float x) {
    float ax  = fabsf(x);
    float eax = __expf(-ax);
    float l1  = __logf(1.f + eax);
    float sp  = fmaxf(x, 0.f) + l1;          // softplus(x)
    float q   = __builtin_amdgcn_rcpf(1.f + eax);
    float p   = (x >= 0.f) ? q : eax * q;    // sigmoid(x)
    return 0.75f * p * p * sp;
}
// positive term: 0.25 * (1-p)^2 * softplus(-x)
__device__ __forceinline__ float focal_pos(float x) {
    float ax  = fabsf(x);
    float eax = __expf(-ax);
    float l1  = __logf(1.f + eax);
    float spn = fmaxf(-x, 0.f) + l1;         // softplus(-x)
    float q   = __builtin_amdgcn_rcpf(1.f + eax);
    float p   = (x >= 0.f) ? q : eax * q;
    float om  = 1.f - p;
    return 0.25f * om * om * spn;
}

// ---------- 1) fused: focal streaming (HBM) || windowed topk (VALU) ----------
// grid = 2560 = 512 groups x 5; r<4 -> focal block (2048 total);
// r==4 -> topk block: 4 waves, wave w handles bo = grp*4+w (2048 total).
__global__ __launch_bounds__(256) void fused_main(
    const float4* __restrict__ sc4,      // [NB*NP*NC/4]
    const float4* __restrict__ boxes,    // [NB*NO]
    const float2* __restrict__ priors2,  // [NP*2] (xy at 2*i, wh at 2*i+1)
    const float4* __restrict__ priors4,  // [NP]
    int*   __restrict__ ci,              // [NB*NO*NSLOT]
    float* __restrict__ cp,              // [NB*NO*NSLOT]
    float* __restrict__ partial,         // [2048]
    int total4)
{
    const unsigned bid = blockIdx.x;
    const unsigned grp = bid / 5u, r = bid - grp * 5u;

    if (r < 4u) {
        // ---------------- focal: pure streaming reduction ----------------
        const int fb = (int)(grp * 4u + r);           // 0..2047
        float lsum = 0.f;
        for (int e4 = fb * 256 + threadIdx.x; e4 < total4; e4 += 2048 * 256) {
            const float4 v = sc4[e4];
            lsum += focal_neg(v.x) + focal_neg(v.y) + focal_neg(v.z) + focal_neg(v.w);
        }
        #pragma unroll
        for (int off = 32; off > 0; off >>= 1) lsum += __shfl_down(lsum, off);
        __shared__ float wsum[4];
        const int lane = threadIdx.x & 63, wid = threadIdx.x >> 6;
        if (lane == 0) wsum[wid] = lsum;
        __syncthreads();
        if (threadIdx.x == 0) partial[fb] = wsum[0] + wsum[1] + wsum[2] + wsum[3];
    } else {
        // ---------------- topk: one wave per (b,o), 7x7 window per level ----
        const int lane = threadIdx.x & 63;
        const int bo   = (int)(grp * 4u + (threadIdx.x >> 6));   // 0..2047

        const float4 a = boxes[bo];
        const float gx = (a.x + a.z) * 0.5f, gy = (a.y + a.w) * 0.5f;
        const float area_a = (a.z - a.x) * (a.w - a.y);

        const int FM[5]  = {64, 32, 16, 8, 4};
        const int OFS[5] = {0, 4096, 5120, 5376, 5440};

        #pragma unroll
        for (int l = 0; l < 5; ++l) {
            const int f    = FM[l];
            const int base = OFS[l];
            const int win  = (l < 4) ? 7 : 4;          // 7x7 window; f=4 -> all 16
            const int nc   = win * win;

            int ix0 = 0, iy0 = 0;
            if (l < 4) {
                int ixn = (int)(gx * (float)f);        // gx*f >= 1.6 > 0: trunc=floor
                int iyn = (int)(gy * (float)f);
                ix0 = min(max(ixn - 3, 0), f - 7);
                iy0 = min(max(iyn - 3, 0), f - 7);
            }

            const bool act = lane < nc;
            const int wx = act ? (lane % win) : 0;
            const int wy = act ? (lane / win) : 0;
            const int lidx = (iy0 + wy) * f + (ix0 + wx);   // level-local prior idx

            float2 pc = priors2[(size_t)(base + lidx) * 2]; // prior center (exact input values)
            float dx = gx - pc.x, dy = gy - pc.y;
            float d = act ? __fsqrt_rn(__fadd_rn(__fmul_rn(dx, dx), __fmul_rn(dy, dy)))
                          : INF;
            int   ki = act ? lidx : 0x7fffffff;

            // exact rank under lex (d, idx): candidates with smaller key
            int rank = 0;
            for (int j = 0; j < nc; ++j) {
                float dj = __shfl(d, j);
                int   ij = __shfl(ki, j);
                rank += (dj < d || (dj == d && ij < ki)) ? 1 : 0;
            }

            if (act && rank < 9) {
                const int gp = base + lidx;
                float4 pv = priors4[gp];
                float bx0 = pv.x - pv.z * 0.5f, by0 = pv.y - pv.w * 0.5f;
                float bx1 = pv.x + pv.z * 0.5f, by1 = pv.y + pv.w * 0.5f;
                float w = fmaxf(fminf(a.z, bx1) - fmaxf(a.x, bx0), 0.f);
                float h = fmaxf(fminf(a.w, by1) - fmaxf(a.y, by0), 0.f);
                float inter  = w * h;
                float area_b = (bx1 - bx0) * (by1 - by0);
                float iou = inter / (area_a + area_b - inter + EPSF);
                const int slot = bo * NSLOT + l * 9 + rank;
                ci[slot] = gp;
                cp[slot] = iou;
            }
        }
    }
}

// ---------- 2) threshold + argmax + decode + ciou + label corr (1 wave/image) ----
__global__ __launch_bounds__(64) void finish_kernel(
    const float4* __restrict__ locs,     // [NB*NP]
    const float4* __restrict__ boxes,    // [NB*NO]
    const int*    __restrict__ labels,   // [NB*NO]
    const float4* __restrict__ priors,   // [NP]
    const float*  __restrict__ scores,   // [NB*NP*NC]
    const int*    __restrict__ ci,
    const float*  __restrict__ cp,
    float* __restrict__ corr,            // [NB] focal pos-correction sum
    int*   __restrict__ npb,             // [NB] distinct positive priors
    float* __restrict__ ciouS,           // [NB] ciou loss sum
    int*   __restrict__ ciouC)           // [NB] matched slot count
{
    const int b = blockIdx.x;
    const int t = threadIdx.x;           // 64 threads = 1 wave

    __shared__ int    s_ci[NO * NSLOT];
    __shared__ float  s_io[NO * NSLOT];
    __shared__ int    s_pidx[NSLOT], s_ob[NSLOT], s_match[NSLOT];
    __shared__ float4 s_dec[NSLOT];

    const int4*   gci = (const int4*)(ci + b * NO * NSLOT);
    const float4* gcp = (const float4*)(cp + b * NO * NSLOT);
    int4*   sci4 = (int4*)s_ci;
    float4* sio4 = (float4*)s_io;
    for (int k = t; k < NO * NSLOT / 4; k += 64) { sci4[k] = gci[k]; sio4[k] = gcp[k]; }
    __syncthreads();

    // per-GT threshold (mean + std ddof=1 over 45) and masked iou (in place)
    if (t < NO) {
        float sum = 0.f;
        #pragma unroll
        for (int k = 0; k < NSLOT; ++k) sum += s_io[t * NSLOT + k];
        float mean = sum / 45.f;
        float var = 0.f;
        #pragma unroll
        for (int k = 0; k < NSLOT; ++k) { float d = s_io[t * NSLOT + k] - mean; var += d * d; }
        float thr = mean + sqrtf(var / 44.f);
        float4 a = boxes[b * NO + t];
        for (int k = 0; k < NSLOT; ++k) {
            float4 pv = priors[s_ci[t * NSLOT + k]];
            bool inside = (a.x < pv.x) && (pv.x < a.z) && (a.y < pv.y) && (pv.y < a.w);
            float pov = s_io[t * NSLOT + k];
            s_io[t * NSLOT + k] = (pov > thr && inside) ? pov : 0.f;
        }
    }
    __syncthreads();

    // per-slot argmax over GTs (first max), decode
    if (t < NSLOT) {
        float bv = s_io[t]; int ob = 0;
        for (int oo = 1; oo < NO; ++oo) {
            float v = s_io[oo * NSLOT + t];
            if (v > bv) { bv = v; ob = oo; }
        }
        int match = bv > 0.f;
        int pidx = s_ci[ob * NSLOT + t];
        s_pidx[t] = pidx; s_ob[t] = ob; s_match[t] = match;
        float4 lc = locs[b * NP + pidx];
        float4 pv = priors[pidx];
        float cx = lc.x * pv.z / 10.f + pv.x;
        float cy = lc.y * pv.w / 10.f + pv.y;
        float wd = expf(lc.z / 5.f) * pv.z;
        float hd = expf(lc.w / 5.f) * pv.w;
        s_dec[t] = make_float4(cx - wd * 0.5f, cy - hd * 0.5f,
                               cx + wd * 0.5f, cy + hd * 0.5f);
    }
    __syncthreads();

    const int matched = (t < NSLOT) ? s_match[t] : 0;

    // ciou for matched slots
    float cl = 0.f;
    if (matched) {
        float4 p = s_dec[t], t4 = boxes[b * NO + s_ob[t]];
        float pw = p.z - p.x, ph = p.w - p.y;
        float tw = t4.z - t4.x, th = t4.w - t4.y;
        float iw = fmaxf(fminf(p.z, t4.z) - fmaxf(p.x, t4.x), 0.f);
        float ih = fmaxf(fminf(p.w, t4.w) - fmaxf(p.y, t4.y), 0.f);
        float inter = iw * ih;
        float uni = pw * ph + tw * th - inter;
        float iou = inter / (uni + EPSF);
        float cw = fmaxf(p.z, t4.z) - fminf(p.x, t4.x);
        float ch = fmaxf(p.w, t4.w) - fminf(p.y, t4.y);
        float c2 = cw * cw + ch * ch + EPSF;
        float ddx = p.x + p.z - t4.x - t4.z, ddy = p.y + p.w - t4.y - t4.w;
        float rho2 = (ddx * ddx + ddy * ddy) * 0.25f;
        float dv = atanf(tw / (th + EPSF)) - atanf(pw / (ph + EPSF));
        float v = (float)(4.0 / (M_PI * M_PI)) * dv * dv;
        float al = v / (1.f - iou + v + EPSF);
        cl = 1.f - iou + rho2 / c2 + al * v;
    }

    // last-writer-wins label resolution -> focal pos-correction; first-occ count
    float mycorr = 0.f; int firstocc = 0;
    if (matched) {
        bool last = true, first = true;
        for (int s2 = t + 1; s2 < NSLOT; ++s2)
            if (s_match[s2] && s_pidx[s2] == s_pidx[t]) last = false;
        for (int s2 = 0; s2 < t; ++s2)
            if (s_match[s2] && s_pidx[s2] == s_pidx[t]) first = false;
        if (last) {
            int lab = labels[b * NO + s_ob[t]];
            float x = scores[((size_t)b * NP + s_pidx[t]) * NC + (lab - 1)];
            mycorr = focal_pos(x) - focal_neg(x);
        }
        firstocc = first;
    }

    unsigned long long ballm = __ballot(matched);
    unsigned long long ballf = __ballot(firstocc);
    #pragma unroll
    for (int off = 32; off > 0; off >>= 1) {
        cl     += __shfl_down(cl, off);
        mycorr += __shfl_down(mycorr, off);
    }
    if (t == 0) {
        corr[b]  = mycorr;
        npb[b]   = (int)__popcll(ballf);
        ciouS[b] = cl;
        ciouC[b] = (int)__popcll(ballm);
    }
}

// ---------- 3) final combine (single block) ----------
__global__ __launch_bounds__(256) void combine_kernel(
    const float* __restrict__ partial,   // [2048]
    const float* __restrict__ corr,      // [NB]
    const int*   __restrict__ npb,       // [NB]
    const float* __restrict__ ciouS,     // [NB]
    const int*   __restrict__ ciouC,     // [NB]
    float* __restrict__ out)
{
    const int t = threadIdx.x;
    double fsum = 0.0;
    for (int i = t; i < 2048; i += 256) fsum += (double)partial[i];

    float crs = 0.f, cs = 0.f; int np = 0, cc = 0;
    if (t < NB) { crs = corr[t]; np = npb[t]; cs = ciouS[t]; cc = ciouC[t]; }

    #pragma unroll
    for (int off = 32; off > 0; off >>= 1) {
        fsum += __shfl_down(fsum, off);
        crs  += __shfl_down(crs, off);
        cs   += __shfl_down(cs, off);
        np   += __shfl_down(np, off);
        cc   += __shfl_down(cc, off);
    }
    __shared__ double sd[4];
    const int lane = t & 63, wid = t >> 6;
    if (lane == 0) sd[wid] = fsum;
    __syncthreads();
    if (t == 0) {
        double ftot = sd[0] + sd[1] + sd[2] + sd[3] + (double)crs;
        int npv = np < 1 ? 1 : np;
        int ccv = cc < 1 ? 1 : cc;
        out[0] = (float)(ftot / (double)npv + (double)cs / (double)ccv);
    }
}

extern "C" void kernel_launch(void* const* d_in, const int* in_sizes, int n_in,
                              void* d_out, int out_size, void* d_ws, size_t ws_size,
                              hipStream_t stream)
{
    const float* locs   = (const float*)d_in[0];
    const float* scores = (const float*)d_in[1];
    const float* boxes  = (const float*)d_in[2];
    const int*   labels = (const int*)d_in[3];
    const float* priors = (const float*)d_in[4];

    char* ws = (char*)d_ws;
    int*   ci      = (int*)(ws + 0);                      // 92160 ints = 368640 B
    float* cp      = (float*)(ws + 368640);               // 368640 B
    float* partial = (float*)(ws + 737280);               // 8192 B
    float* corr    = (float*)(ws + 745472);
    int*   npb     = (int*)(ws + 745728);
    float* ciouS   = (float*)(ws + 745984);
    int*   ciouC   = (int*)(ws + 746240);

    // no memsets: partial/corr/npb/ciouS/ciouC written unconditionally each
    // call; all 45 ci/cp slots per (b,o) written every call (ranks 0..8 of a
    // total order always exist). Deterministic across replays.

    const int total4 = NB * NP * NC / 4;
    fused_main<<<2560, 256, 0, stream>>>(
        (const float4*)scores, (const float4*)boxes,
        (const float2*)priors, (const float4*)priors,
        ci, cp, partial, total4);

    finish_kernel<<<NB, 64, 0, stream>>>(
        (const float4*)locs, (const float4*)boxes, labels,
        (const float4*)priors, scores, ci, cp, corr, npb, ciouS, ciouC);

    combine_kernel<<<1, 256, 0, stream>>>(partial, corr, npb, ciouS, ciouC, (float*)d_out);
}